// Round 6
// baseline (146.202 us; speedup 1.0000x reference)
//
#include <hip/hip_runtime.h>

#define NV 12
#define CIN 384
#define COUT 32
#define HW 4096        // 64*64 feature pixels
#define NVOX 262144    // 64^3 voxels
#define KSTEPS 12      // 384 / 32
#define KSTEP 32
#define KPAD 33        // +1 pad: ds bank rotation
#define PIXB 64        // pixels per block (4 waves x 16)
#define ZROW_U4 786432 // uint4 index of the 64B zero row (= 48*4096*32 bf16 / 8)

typedef __attribute__((ext_vector_type(8))) short short8v;   // 8 bf16 (4 VGPR)
typedef __attribute__((ext_vector_type(4))) short short4v;   // 4 bf16 (2 VGPR)
typedef __attribute__((ext_vector_type(4))) float f32x4;     // MFMA accum

// fp32 -> bf16 bits, round-to-nearest-even (finite data; NaN not handled).
__device__ __forceinline__ short bf16b(float x) {
    union { float f; unsigned u; } c; c.f = x;
    unsigned r = (c.u + 0x7fffu + ((c.u >> 16) & 1u)) >> 16;
    return (short)r;
}

// Prep: repack W into MFMA A-fragment order (bf16) + zero the fuse zero-row.
__global__ __launch_bounds__(256) void w_prep_kernel(
    const float* __restrict__ w, short* __restrict__ wfrag,
    short* __restrict__ feats)
{
    const int t = blockIdx.x * 256 + threadIdx.x;
    if (t < 48 * 32) {
        const int sg = t >> 5, o = t & 31;
        const int s = sg >> 2, g = sg & 3;
        short8v v;
#pragma unroll
        for (int i = 0; i < 8; ++i)
            v[i] = bf16b(w[o * CIN + s * 32 + g * 8 + i]);
        *reinterpret_cast<short8v*>(wfrag + t * 8) = v;
    } else if (t >= 1536 && t < 1540) {
        reinterpret_cast<uint4*>(feats)[ZROW_U4 + (t - 1536)] =
            make_uint4(0u, 0u, 0u, 0u);
    }
}

// Kernel 1: channel reduce 384->32 on matrix cores, LDS-staged. (Unchanged.)
__global__ __launch_bounds__(256) void mv_reduce_mfma_kernel(
    const float* __restrict__ vit, const short* __restrict__ wfrag,
    const float* __restrict__ bias, short* __restrict__ feats)
{
    __shared__ float lds[PIXB][KPAD];        // 8448 B

    const int bid  = blockIdx.x;             // 0..3071
    const int bv   = bid >> 6;               // 0..47
    const int pix0 = (bid & 63) * PIXB;

    const int tid  = threadIdx.x;
    const int wave = tid >> 6;
    const int l    = tid & 63;
    const int col  = l & 15;
    const int g    = l >> 4;

    const int kk  = tid >> 4;
    const int px4 = (tid & 15) * 4;

    const float* vbase = vit + (size_t)bv * CIN * HW + pix0;
    const short8v* wf  = reinterpret_cast<const short8v*>(wfrag);

    f32x4 acc0 = {0.f, 0.f, 0.f, 0.f};
    f32x4 acc1 = {0.f, 0.f, 0.f, 0.f};

#pragma unroll
    for (int s = 0; s < KSTEPS; ++s) {
        const float4 r0 = *reinterpret_cast<const float4*>(
            vbase + (size_t)(s * KSTEP + kk) * HW + px4);
        const float4 r1 = *reinterpret_cast<const float4*>(
            vbase + (size_t)(s * KSTEP + kk + 16) * HW + px4);

        __syncthreads();
        lds[px4 + 0][kk] = r0.x;  lds[px4 + 1][kk] = r0.y;
        lds[px4 + 2][kk] = r0.z;  lds[px4 + 3][kk] = r0.w;
        lds[px4 + 0][kk + 16] = r1.x;  lds[px4 + 1][kk + 16] = r1.y;
        lds[px4 + 2][kk + 16] = r1.z;  lds[px4 + 3][kk + 16] = r1.w;
        __syncthreads();

        const float4 f0 = *reinterpret_cast<const float4*>(&lds[wave * 16 + col][8 * g]);
        const float4 f1 = *reinterpret_cast<const float4*>(&lds[wave * 16 + col][8 * g + 4]);

        short8v bfr;
        bfr[0] = bf16b(f0.x); bfr[1] = bf16b(f0.y);
        bfr[2] = bf16b(f0.z); bfr[3] = bf16b(f0.w);
        bfr[4] = bf16b(f1.x); bfr[5] = bf16b(f1.y);
        bfr[6] = bf16b(f1.z); bfr[7] = bf16b(f1.w);

        const short8v a0 = wf[(s * 4 + g) * 32 + col];
        const short8v a1 = wf[(s * 4 + g) * 32 + 16 + col];

        acc0 = __builtin_amdgcn_mfma_f32_16x16x32_bf16(a0, bfr, acc0, 0, 0, 0);
        acc1 = __builtin_amdgcn_mfma_f32_16x16x32_bf16(a1, bfr, acc1, 0, 0, 0);
    }

    short* dst = feats + ((size_t)bv * HW + pix0 + wave * 16 + col) * COUT;
    const float4 b0 = *reinterpret_cast<const float4*>(bias + 4 * g);
    const float4 b1 = *reinterpret_cast<const float4*>(bias + 16 + 4 * g);
    short4v o0, o1;
    o0[0] = bf16b(acc0[0] + b0.x); o0[1] = bf16b(acc0[1] + b0.y);
    o0[2] = bf16b(acc0[2] + b0.z); o0[3] = bf16b(acc0[3] + b0.w);
    o1[0] = bf16b(acc1[0] + b1.x); o1[1] = bf16b(acc1[1] + b1.y);
    o1[2] = bf16b(acc1[2] + b1.z); o1[3] = bf16b(acc1[3] + b1.w);
    *reinterpret_cast<short4v*>(dst + 4 * g) = o0;
    *reinterpret_cast<short4v*>(dst + 16 + 4 * g) = o1;
}

// Kernel 2: two-phase fuse. Phase 1: all 12 projections (fp64, unchanged
// numerics) -> precomputed uint4 gather offsets; invalid views -> zero-row
// (adds exact 0.0, branch-free). Phase 2: 1-deep pipelined gather+accumulate.
__global__ __launch_bounds__(256) void mv_fuse_kernel(
    const unsigned short* __restrict__ feats, const float* __restrict__ proj,
    float* __restrict__ out)
{
    __shared__ double P[NV][12];

    const int tid = threadIdx.x;
    const unsigned gid = blockIdx.x * 256u + tid;
    const int b = gid >> 18;
    const int n = gid & (NVOX - 1);

    if (tid < NV * 12) {
        const int v = tid / 12, e = tid - v * 12;
        const int r = e >> 2;
        const float s = (r < 2) ? 0.25f : 1.0f;
        P[v][e] = (double)(proj[((b * NV + v) * 3 + r) * 4 + (e & 3)] * s);
    }
    __syncthreads();

    const int k = n & 63, j = (n >> 6) & 63, i = n >> 12;
    const double wx = (double)i * 0.04 - 1.28;
    const double wy = (double)j * 0.04 - 1.28;
    const double wz = (double)k * 0.04 - 1.28;

    // Phase 1: projections -> offsets (uint4 units into feats) + valid count.
    int off[NV];
    int cnt = 0;
    const int bbase = b * (NV * HW * 4);
#pragma unroll
    for (int v = 0; v < NV; ++v) {
        const double* p = P[v];
        const double cz = p[8] * wx + p[9] * wy + p[10] * wz + p[11];
        const double cx = p[0] * wx + p[1] * wy + p[2] * wz + p[3];
        const double cy = p[4] * wx + p[5] * wy + p[6] * wz + p[7];
        const double rcz = 1.0 / cz;
        const double u = rint(cx * rcz);   // round-half-even == jnp.round
        const double t = rint(cy * rcz);
        const bool valid = (cz > 0.0) & (u >= 0.0) & (u <= 63.0) &
                           (t >= 0.0) & (t <= 63.0);
        const double uc = fmin(fmax(u, 0.0), 63.0);
        const double tc = fmin(fmax(t, 0.0), 63.0);
        const int pix = (int)uc + 64 * (int)tc;
        off[v] = valid ? (bbase + (v * HW + pix) * 4) : ZROW_U4;
        cnt += valid ? 1 : 0;
    }

    // Phase 2: gather + accumulate, next view's loads in flight over this
    // view's 64 VALU ops.
    float acc[COUT];
#pragma unroll
    for (int o = 0; o < COUT; ++o) acc[o] = 0.0f;

    const uint4* f4 = reinterpret_cast<const uint4*>(feats);
    uint4 c0 = f4[off[0]], c1 = f4[off[0] + 1],
          c2 = f4[off[0] + 2], c3 = f4[off[0] + 3];

#pragma unroll
    for (int v = 0; v < NV; ++v) {
        uint4 n0 = c0, n1 = c1, n2 = c2, n3 = c3;
        if (v + 1 < NV) {
            const int o2 = off[v + 1];
            n0 = f4[o2]; n1 = f4[o2 + 1]; n2 = f4[o2 + 2]; n3 = f4[o2 + 3];
        }
#define ACC8(u4, base)                                          \
        acc[base + 0] += __uint_as_float(u4.x << 16);           \
        acc[base + 1] += __uint_as_float(u4.x & 0xffff0000u);   \
        acc[base + 2] += __uint_as_float(u4.y << 16);           \
        acc[base + 3] += __uint_as_float(u4.y & 0xffff0000u);   \
        acc[base + 4] += __uint_as_float(u4.z << 16);           \
        acc[base + 5] += __uint_as_float(u4.z & 0xffff0000u);   \
        acc[base + 6] += __uint_as_float(u4.w << 16);           \
        acc[base + 7] += __uint_as_float(u4.w & 0xffff0000u);
        ACC8(c0, 0) ACC8(c1, 8) ACC8(c2, 16) ACC8(c3, 24)
#undef ACC8
        c0 = n0; c1 = n1; c2 = n2; c3 = n3;
    }

    const float sc = (cnt > 0) ? (1.0f / (float)cnt) : 0.0f;
    float* ob = out + (size_t)b * COUT * NVOX + n;
#pragma unroll
    for (int o = 0; o < COUT; ++o)
        ob[(size_t)o * NVOX] = acc[o] * sc;
}

extern "C" void kernel_launch(void* const* d_in, const int* in_sizes, int n_in,
                              void* d_out, int out_size, void* d_ws, size_t ws_size,
                              hipStream_t stream) {
    const float* vit  = (const float*)d_in[0];  // (4,12,384,64,64)
    const float* w    = (const float*)d_in[1];  // (32,384)
    const float* bias = (const float*)d_in[2];  // (32,)
    const float* proj = (const float*)d_in[3];  // (4,12,3,4)
    float* out = (float*)d_out;                 // (4,32,64,64,64)

    short* wfrag = (short*)d_ws;                            // 24 KB
    short* feats = (short*)((char*)d_ws + 48 * 32 * 8 * 2); // bf16 12.6 MB + 64B zero row

    w_prep_kernel<<<7, 256, 0, stream>>>(w, wfrag, feats);

    mv_reduce_mfma_kernel<<<3072, 256, 0, stream>>>(vit, wfrag, bias, feats);

    mv_fuse_kernel<<<4096, 256, 0, stream>>>(
        (const unsigned short*)feats, proj, out);
}

// Round 7
// 130.881 us; speedup vs baseline: 1.1171x; 1.1171x over previous
//
#include <hip/hip_runtime.h>

#define NV 12
#define CIN 384
#define COUT 32
#define HW 4096        // 64*64 feature pixels
#define NVOX 262144    // 64^3 voxels
#define KSTEPS 12      // 384 / 32
#define KSTEP 32
#define KPAD 33        // +1 pad: ds bank rotation
#define PIXB 128       // pixels per block (4 waves x 2 x 16)

typedef __attribute__((ext_vector_type(8))) short short8v;   // 8 bf16 (4 VGPR)
typedef __attribute__((ext_vector_type(4))) short short4v;   // 4 bf16 (2 VGPR)
typedef __attribute__((ext_vector_type(4))) float f32x4;     // MFMA accum

// fp32 -> bf16 bits, round-to-nearest-even (finite data; NaN not handled).
__device__ __forceinline__ short bf16b(float x) {
    union { float f; unsigned u; } c; c.f = x;
    unsigned r = (c.u + 0x7fffu + ((c.u >> 16) & 1u)) >> 16;
    return (short)r;
}

// Prep: repack W (32x384 fp32) into MFMA A-fragment order, bf16:
// wfrag[((s*4+g)*32 + o)*8 + i] = bf16(w[o*384 + s*32 + g*8 + i])
__global__ __launch_bounds__(256) void w_prep_kernel(
    const float* __restrict__ w, short* __restrict__ wfrag)
{
    const int t = blockIdx.x * 256 + threadIdx.x;   // 0..1535
    const int sg = t >> 5, o = t & 31;
    const int s = sg >> 2, g = sg & 3;
    short8v v;
#pragma unroll
    for (int i = 0; i < 8; ++i)
        v[i] = bf16b(w[o * CIN + s * 32 + g * 8 + i]);
    *reinterpret_cast<short8v*>(wfrag + t * 8) = v;
}

// Kernel 1: channel reduce 384->32 on matrix cores, LDS-staged, 128-pix tile.
// Grid 1536 = 6 blocks/CU exactly. Per k-step each thread stages 4 float4
// (lanes 0-15 cover 256B contiguous per k-row; 1KB/wave-inst), LDS transposed
// [pix][k] (+1 pad -> 2-way banks, free), each wave computes 2 pixel-tiles x
// 2 o-tiles = 4 MFMAs. Barriers per staged byte halved vs 64-pix tile.
__global__ __launch_bounds__(256) void mv_reduce_mfma_kernel(
    const float* __restrict__ vit, const short* __restrict__ wfrag,
    const float* __restrict__ bias, short* __restrict__ feats)
{
    __shared__ float lds[PIXB][KPAD];        // 16896 B -> 6+ blocks/CU

    const int bid  = blockIdx.x;             // 0..1535
    const int bv   = bid >> 5;               // 0..47
    const int pix0 = (bid & 31) * PIXB;

    const int tid  = threadIdx.x;
    const int wave = tid >> 6;               // 0..3
    const int l    = tid & 63;
    const int col  = l & 15;                 // pixel-in-tile / o-in-tile
    const int g    = l >> 4;                 // k-group

    const int kk  = tid >> 4;                // staging k-row 0..15
    const int px4 = (tid & 15) * 4;          // staging pixel quad 0..60

    const float* vbase = vit + (size_t)bv * CIN * HW + pix0;
    const short8v* wf  = reinterpret_cast<const short8v*>(wfrag);

    f32x4 acc00 = {0.f, 0.f, 0.f, 0.f};     // pix tile 0, o 0-15
    f32x4 acc01 = {0.f, 0.f, 0.f, 0.f};     // pix tile 0, o 16-31
    f32x4 acc10 = {0.f, 0.f, 0.f, 0.f};     // pix tile 1, o 0-15
    f32x4 acc11 = {0.f, 0.f, 0.f, 0.f};     // pix tile 1, o 16-31

#pragma unroll
    for (int s = 0; s < KSTEPS; ++s) {
        const float* r0base = vbase + (size_t)(s * KSTEP + kk) * HW;
        const float* r1base = vbase + (size_t)(s * KSTEP + kk + 16) * HW;
        const float4 r00 = *reinterpret_cast<const float4*>(r0base + px4);
        const float4 r01 = *reinterpret_cast<const float4*>(r0base + px4 + 64);
        const float4 r10 = *reinterpret_cast<const float4*>(r1base + px4);
        const float4 r11 = *reinterpret_cast<const float4*>(r1base + px4 + 64);

        __syncthreads();                     // prior iteration's reads done
        lds[px4 + 0][kk] = r00.x;  lds[px4 + 1][kk] = r00.y;
        lds[px4 + 2][kk] = r00.z;  lds[px4 + 3][kk] = r00.w;
        lds[px4 + 64][kk] = r01.x; lds[px4 + 65][kk] = r01.y;
        lds[px4 + 66][kk] = r01.z; lds[px4 + 67][kk] = r01.w;
        lds[px4 + 0][kk + 16] = r10.x;  lds[px4 + 1][kk + 16] = r10.y;
        lds[px4 + 2][kk + 16] = r10.z;  lds[px4 + 3][kk + 16] = r10.w;
        lds[px4 + 64][kk + 16] = r11.x; lds[px4 + 65][kk + 16] = r11.y;
        lds[px4 + 66][kk + 16] = r11.z; lds[px4 + 67][kk + 16] = r11.w;
        __syncthreads();                     // writes visible

        const float4 f0a = *reinterpret_cast<const float4*>(&lds[wave * 32 + col][8 * g]);
        const float4 f0b = *reinterpret_cast<const float4*>(&lds[wave * 32 + col][8 * g + 4]);
        const float4 f1a = *reinterpret_cast<const float4*>(&lds[wave * 32 + 16 + col][8 * g]);
        const float4 f1b = *reinterpret_cast<const float4*>(&lds[wave * 32 + 16 + col][8 * g + 4]);

        short8v bfr0, bfr1;
        bfr0[0] = bf16b(f0a.x); bfr0[1] = bf16b(f0a.y);
        bfr0[2] = bf16b(f0a.z); bfr0[3] = bf16b(f0a.w);
        bfr0[4] = bf16b(f0b.x); bfr0[5] = bf16b(f0b.y);
        bfr0[6] = bf16b(f0b.z); bfr0[7] = bf16b(f0b.w);
        bfr1[0] = bf16b(f1a.x); bfr1[1] = bf16b(f1a.y);
        bfr1[2] = bf16b(f1a.z); bfr1[3] = bf16b(f1a.w);
        bfr1[4] = bf16b(f1b.x); bfr1[5] = bf16b(f1b.y);
        bfr1[6] = bf16b(f1b.z); bfr1[7] = bf16b(f1b.w);

        const short8v a0 = wf[(s * 4 + g) * 32 + col];        // o = col
        const short8v a1 = wf[(s * 4 + g) * 32 + 16 + col];   // o = 16 + col

        acc00 = __builtin_amdgcn_mfma_f32_16x16x32_bf16(a0, bfr0, acc00, 0, 0, 0);
        acc01 = __builtin_amdgcn_mfma_f32_16x16x32_bf16(a1, bfr0, acc01, 0, 0, 0);
        acc10 = __builtin_amdgcn_mfma_f32_16x16x32_bf16(a0, bfr1, acc10, 0, 0, 0);
        acc11 = __builtin_amdgcn_mfma_f32_16x16x32_bf16(a1, bfr1, acc11, 0, 0, 0);
    }

    // Store bf16: feats[bv][pix][o]; lane's 4 accum elems are o = 4g+r.
    const float4 b0 = *reinterpret_cast<const float4*>(bias + 4 * g);
    const float4 b1 = *reinterpret_cast<const float4*>(bias + 16 + 4 * g);
    short* dst0 = feats + ((size_t)bv * HW + pix0 + wave * 32 + col) * COUT;
    short* dst1 = dst0 + 16 * COUT;
    short4v o00, o01, o10, o11;
    o00[0] = bf16b(acc00[0] + b0.x); o00[1] = bf16b(acc00[1] + b0.y);
    o00[2] = bf16b(acc00[2] + b0.z); o00[3] = bf16b(acc00[3] + b0.w);
    o01[0] = bf16b(acc01[0] + b1.x); o01[1] = bf16b(acc01[1] + b1.y);
    o01[2] = bf16b(acc01[2] + b1.z); o01[3] = bf16b(acc01[3] + b1.w);
    o10[0] = bf16b(acc10[0] + b0.x); o10[1] = bf16b(acc10[1] + b0.y);
    o10[2] = bf16b(acc10[2] + b0.z); o10[3] = bf16b(acc10[3] + b0.w);
    o11[0] = bf16b(acc11[0] + b1.x); o11[1] = bf16b(acc11[1] + b1.y);
    o11[2] = bf16b(acc11[2] + b1.z); o11[3] = bf16b(acc11[3] + b1.w);
    *reinterpret_cast<short4v*>(dst0 + 4 * g) = o00;
    *reinterpret_cast<short4v*>(dst0 + 16 + 4 * g) = o01;
    *reinterpret_cast<short4v*>(dst1 + 4 * g) = o10;
    *reinterpret_cast<short4v*>(dst1 + 16 + 4 * g) = o11;
}

// Kernel 2: backproject + gather (bf16 rows, 64B aligned) + average.
// R5 form (serial view loop — fp64 of view v+1 overlaps view v's gather
// latency naturally; do NOT restructure, R6 showed it regresses).
__global__ __launch_bounds__(256) void mv_fuse_kernel(
    const unsigned short* __restrict__ feats, const float* __restrict__ proj,
    float* __restrict__ out)
{
    __shared__ double P[NV][12];

    const int tid = threadIdx.x;
    const unsigned gid = blockIdx.x * 256u + tid;
    const int b = gid >> 18;
    const int n = gid & (NVOX - 1);

    if (tid < NV * 12) {
        const int v = tid / 12, e = tid - v * 12;
        const int r = e >> 2;
        const float s = (r < 2) ? 0.25f : 1.0f;
        P[v][e] = (double)(proj[((b * NV + v) * 3 + r) * 4 + (e & 3)] * s);
    }
    __syncthreads();

    const int k = n & 63, j = (n >> 6) & 63, i = n >> 12;
    const double wx = (double)i * 0.04 - 1.28;
    const double wy = (double)j * 0.04 - 1.28;
    const double wz = (double)k * 0.04 - 1.28;

    float acc[COUT];
#pragma unroll
    for (int o = 0; o < COUT; ++o) acc[o] = 0.0f;
    int cnt = 0;

    const unsigned short* fb = feats + (size_t)b * NV * HW * COUT;

    for (int v = 0; v < NV; ++v) {
        const double* p = P[v];
        const double cz = p[8] * wx + p[9] * wy + p[10] * wz + p[11];
        if (!(cz > 0.0)) continue;
        const double cx = p[0] * wx + p[1] * wy + p[2] * wz + p[3];
        const double cy = p[4] * wx + p[5] * wy + p[6] * wz + p[7];
        const double rcz = 1.0 / cz;
        const double u = rint(cx * rcz);   // round-half-even == jnp.round
        const double t = rint(cy * rcz);
        if (u < 0.0 || u > 63.0 || t < 0.0 || t > 63.0) continue;
        const int px = (int)u, py = (int)t;

        const uint4* s4 = reinterpret_cast<const uint4*>(
            fb + ((size_t)(v * HW + py * 64 + px)) * COUT);
        ++cnt;
#pragma unroll
        for (int q = 0; q < 4; ++q) {
            const uint4 u4 = s4[q];
            acc[q * 8 + 0] += __uint_as_float(u4.x << 16);
            acc[q * 8 + 1] += __uint_as_float(u4.x & 0xffff0000u);
            acc[q * 8 + 2] += __uint_as_float(u4.y << 16);
            acc[q * 8 + 3] += __uint_as_float(u4.y & 0xffff0000u);
            acc[q * 8 + 4] += __uint_as_float(u4.z << 16);
            acc[q * 8 + 5] += __uint_as_float(u4.z & 0xffff0000u);
            acc[q * 8 + 6] += __uint_as_float(u4.w << 16);
            acc[q * 8 + 7] += __uint_as_float(u4.w & 0xffff0000u);
        }
    }

    const float sc = (cnt > 0) ? (1.0f / (float)cnt) : 0.0f;
    float* ob = out + (size_t)b * COUT * NVOX + n;
#pragma unroll
    for (int o = 0; o < COUT; ++o)
        ob[(size_t)o * NVOX] = acc[o] * sc;
}

extern "C" void kernel_launch(void* const* d_in, const int* in_sizes, int n_in,
                              void* d_out, int out_size, void* d_ws, size_t ws_size,
                              hipStream_t stream) {
    const float* vit  = (const float*)d_in[0];  // (4,12,384,64,64)
    const float* w    = (const float*)d_in[1];  // (32,384)
    const float* bias = (const float*)d_in[2];  // (32,)
    const float* proj = (const float*)d_in[3];  // (4,12,3,4)
    float* out = (float*)d_out;                 // (4,32,64,64,64)

    short* wfrag = (short*)d_ws;                            // 24 KB
    short* feats = (short*)((char*)d_ws + 48 * 32 * 8 * 2); // bf16, 12.6 MB

    w_prep_kernel<<<6, 256, 0, stream>>>(w, wfrag);

    mv_reduce_mfma_kernel<<<1536, 256, 0, stream>>>(vit, wfrag, bias, feats);

    mv_fuse_kernel<<<4096, 256, 0, stream>>>(
        (const unsigned short*)feats, proj, out);
}